// Round 17
// baseline (1123.059 us; speedup 1.0000x reference)
//
#include <hip/hip_runtime.h>

#define TT 256
#define II 30
#define HH 128
#define TB 8            // samples per WG -> 512 WGs, 2 WGs/CU (indep barrier domains)
#define HROWF 136       // f16 stride for h panel rows (272B)
#define XROWF 40        // f16 stride for x panel rows (80B)
#define XTT 8           // timesteps per staged window
#define XPANEL (XTT * TB * XROWF)   // 2560 f16 per buffer

typedef _Float16 half8 __attribute__((ext_vector_type(8)));
typedef float f32x4 __attribute__((ext_vector_type(4)));

#define EXP2(x) __builtin_amdgcn_exp2f(x)
#define RCP(x) __builtin_amdgcn_rcpf(x)
#define L2E 1.44269504089f
#define TWO_L2E 2.88539008177f

// 256 threads = 4 waves (1/SIMD per WG). (256,2) caps VGPR at 256 so TWO WGs
// co-reside per CU -> two independent barrier domains drift and overlap pipes.
__global__ __launch_bounds__(256, 2)
void lstm_mfma(const float* __restrict__ x,
               const float* __restrict__ W_ih,
               const float* __restrict__ W_hh,
               const float* __restrict__ b_ih,
               const float* __restrict__ b_hh,
               const float* __restrict__ W0,
               const float* __restrict__ b0v,
               const float* __restrict__ W1,
               const float* __restrict__ b1v,
               float* __restrict__ out)
{
  __shared__ __align__(16) _Float16 Hb[2][TB * HROWF];   // 4.3 KB
  __shared__ __align__(16) _Float16 Xp[2][XPANEL];       // 10 KB
  __shared__ float y0ls[TB * 132];

  const int tid = threadIdx.x;
  const int bbase = blockIdx.x * TB;
  const int wv = tid >> 6;      // wave 0..3: owns units wv*32 .. wv*32+31 (x4 gates)
  const int lane = tid & 63;
  const int col = lane & 15;
  const int grp = lane >> 4;
  const int row8 = col & 7;     // dup-row A-reads (r13-proven): rows 8-15 mirror 0-7

  // ---- B-fragments: 8 tiles t = g*2+uh, unit n = g*128 + wv*32 + uh*16 + col.
  // Lane holds all 4 gates of units (wv*32 + uh*16 + col) -> gate math lane-local.
  half8 bf[8][5];
  float bias[8];
  #pragma unroll
  for (int g = 0; g < 4; ++g) {
    const float sc0 = (g == 2) ? TWO_L2E : L2E;
    #pragma unroll
    for (int uh = 0; uh < 2; ++uh) {
      const int t = g * 2 + uh;
      const int n = g * 128 + wv * 32 + uh * 16 + col;
      #pragma unroll
      for (int ks = 0; ks < 4; ++ks) {
        const float4 p = *reinterpret_cast<const float4*>(W_hh + n * HH + ks * 32 + grp * 8);
        const float4 q = *reinterpret_cast<const float4*>(W_hh + n * HH + ks * 32 + grp * 8 + 4);
        bf[t][ks] = (half8){(_Float16)(p.x * sc0), (_Float16)(p.y * sc0),
                            (_Float16)(p.z * sc0), (_Float16)(p.w * sc0),
                            (_Float16)(q.x * sc0), (_Float16)(q.y * sc0),
                            (_Float16)(q.z * sc0), (_Float16)(q.w * sc0)};
      }
      {
        float v[8];
        #pragma unroll
        for (int j = 0; j < 8; ++j) {
          const int cc = grp * 8 + j;
          v[j] = (cc < II) ? W_ih[n * II + cc] * sc0 : 0.0f;
        }
        bf[t][4] = (half8){(_Float16)v[0], (_Float16)v[1], (_Float16)v[2], (_Float16)v[3],
                           (_Float16)v[4], (_Float16)v[5], (_Float16)v[6], (_Float16)v[7]};
      }
      bias[t] = (b_ih[n] + b_hh[n]) * sc0;
    }
  }

  // ---- x stager: 240 threads x 8 consecutive floats per window (XTT=8) ----
  const bool stg = (tid < 240);
  const int sS = stg ? (tid / 30) : 7;   // sample 0..7
  const int qS = tid % 30;
  const int g0 = qS * 8;                 // 32B-aligned float offset in window
  const int tt0 = g0 / II;
  const int i00 = g0 % II;
  const float* wbase = x + (size_t)(bbase + sS) * (TT * II);

  float4 xr0, xr1;
  auto xload = [&](int win) {
    if (!stg) return;
    const float* p = wbase + win * (XTT * II) + g0;
    xr0 = *reinterpret_cast<const float4*>(p);
    xr1 = *reinterpret_cast<const float4*>(p + 4);
  };
  auto xwrite = [&](int dstb) {
    if (!stg) return;
    _Float16* d = &Xp[dstb][0];
    const float vv[8] = {xr0.x, xr0.y, xr0.z, xr0.w, xr1.x, xr1.y, xr1.z, xr1.w};
    int tt = tt0, i = i00;
    #pragma unroll
    for (int j = 0; j < 8; ++j) {
      d[tt * (TB * XROWF) + sS * XROWF + i] = (_Float16)vv[j];
      ++i;
      if (i == II) { i = 0; ++tt; }
    }
  };

  // ---- zero Hb (h(0)=0) AND Xp (pad cols: f16 garbage can be inf/NaN; NaN*0=NaN) ----
  {
    _Float16* hflat = &Hb[0][0];            // 2*8*136 = 2176 f16
    for (int i8 = tid; i8 < (2 * TB * HROWF) / 8; i8 += 256)
      *reinterpret_cast<half8*>(hflat + i8 * 8) = (half8){0,0,0,0,0,0,0,0};
    _Float16* xflat = &Xp[0][0];            // 2*2560 = 5120 f16
    for (int i8 = tid; i8 < (2 * XPANEL) / 8; i8 += 256)
      *reinterpret_cast<half8*>(xflat + i8 * 8) = (half8){0,0,0,0,0,0,0,0};
  }

  float c[4] = {0.0f, 0.0f, 0.0f, 0.0f};   // c[uh*2+rr]
  const int rb = grp & 2;                  // r13-proven gate split

  xload(0);
  __syncthreads();   // zero-init visible before window-0 writes
  xwrite(0);
  __syncthreads();

  auto step = [&](int tt_idx, const _Float16* Ar, _Float16* Aw, const _Float16* Xr) {
    half8 af[5];
    #pragma unroll
    for (int ks = 0; ks < 4; ++ks)
      af[ks] = *reinterpret_cast<const half8*>(&Ar[row8 * HROWF + ks * 32 + grp * 8]);
    af[4] = *reinterpret_cast<const half8*>(&Xr[tt_idx * (TB * XROWF) + row8 * XROWF + grp * 8]);

    f32x4 acc[8];
    #pragma unroll
    for (int t = 0; t < 8; ++t)
      acc[t] = (f32x4){bias[t], bias[t], bias[t], bias[t]};
    #pragma unroll
    for (int ks = 0; ks < 5; ++ks)
      #pragma unroll
      for (int t = 0; t < 8; ++t)
        acc[t] = __builtin_amdgcn_mfma_f32_16x16x32_f16(af[ks], bf[t][ks], acc[t], 0, 0, 0);

    // fused gates (r13-proven): 4 real quads/lane = 2 units (uh) x 2 samples (rr)
    #pragma unroll
    for (int uh = 0; uh < 2; ++uh) {
      #pragma unroll
      for (int rr = 0; rr < 2; ++rr) {
        const int r = rb + rr;
        const float p0 = acc[uh][r];       // i
        const float p1 = acc[2 + uh][r];   // f
        const float p2 = acc[4 + uh][r];   // g
        const float p3 = acc[6 + uh][r];   // o
        const float Ei = EXP2(-p0);
        const float Ef = EXP2(-p1);
        const float Eg = EXP2(fminf(p2, 126.0f));
        const float Eo = EXP2(-p3);
        const float ig = (Eg - 1.0f) * RCP((1.0f + Ei) * (Eg + 1.0f));
        const float ff = RCP(1.0f + Ef);
        const float cn = fmaf(ff, c[uh * 2 + rr], ig);
        c[uh * 2 + rr] = cn;
        const float Ec = EXP2(fminf(cn * TWO_L2E, 126.0f));
        const float oth = (Ec - 1.0f) * RCP((1.0f + Eo) * (Ec + 1.0f));
        Aw[((grp * 4 + r) & 7) * HROWF + wv * 32 + uh * 16 + col] = (_Float16)oth;
      }
    }
    __syncthreads();
  };

  // ================= recurrence: 32 windows x 8 steps =================
  for (int win = 0; win < 32; ++win) {
    const _Float16* Xr = &Xp[win & 1][0];
    if (win + 1 < 32) xload(win + 1);
    step(0, &Hb[0][0], &Hb[1][0], Xr);
    step(1, &Hb[1][0], &Hb[0][0], Xr);
    step(2, &Hb[0][0], &Hb[1][0], Xr);
    step(3, &Hb[1][0], &Hb[0][0], Xr);
    if (win + 1 < 32) xwrite((win + 1) & 1);   // other buffer: unread this window
    step(4, &Hb[0][0], &Hb[1][0], Xr);
    step(5, &Hb[1][0], &Hb[0][0], Xr);
    step(6, &Hb[0][0], &Hb[1][0], Xr);
    step(7, &Hb[1][0], &Hb[0][0], Xr);
  }

  // ================= head =================
  if (tid < TB * 16) {
    const int s = tid >> 4;          // 0..7
    const int n0 = (tid & 15) * 8;
    float acch[8];
    #pragma unroll
    for (int nj = 0; nj < 8; ++nj) acch[nj] = b0v[n0 + nj];
    #pragma unroll
    for (int kb = 0; kb < 16; ++kb) {
      const half8 hh = *reinterpret_cast<const half8*>(&Hb[0][s * HROWF + kb * 8]);
      float hf[8];
      #pragma unroll
      for (int j = 0; j < 8; ++j) hf[j] = (float)hh[j];
      #pragma unroll
      for (int nj = 0; nj < 8; ++nj) {
        const float4 w0 = *reinterpret_cast<const float4*>(W0 + (n0 + nj) * HH + kb * 8);
        const float4 w1 = *reinterpret_cast<const float4*>(W0 + (n0 + nj) * HH + kb * 8 + 4);
        acch[nj] = fmaf(hf[0], w0.x, fmaf(hf[1], w0.y, fmaf(hf[2], w0.z, fmaf(hf[3], w0.w,
                   fmaf(hf[4], w1.x, fmaf(hf[5], w1.y, fmaf(hf[6], w1.z, fmaf(hf[7], w1.w,
                        acch[nj]))))))));
      }
    }
    #pragma unroll
    for (int nj = 0; nj < 8; ++nj)
      y0ls[s * 132 + n0 + nj] = fmaxf(acch[nj], 0.0f);
  }
  __syncthreads();

  if (tid < TB * 11) {
    const int s = tid / 11;
    const int oo = tid % 11;
    float acc1 = b1v[oo];
    const float4* y4 = reinterpret_cast<const float4*>(y0ls + s * 132);
    const float4* w4 = reinterpret_cast<const float4*>(W1 + oo * HH);
    #pragma unroll 8
    for (int k4 = 0; k4 < 32; ++k4) {
      const float4 yv = y4[k4];
      const float4 wv4 = w4[k4];
      acc1 = fmaf(yv.x, wv4.x, fmaf(yv.y, wv4.y, fmaf(yv.z, wv4.z, fmaf(yv.w, wv4.w, acc1))));
    }
    out[(size_t)(bbase + s) * 11 + oo] = acc1;
  }
}

extern "C" void kernel_launch(void* const* d_in, const int* in_sizes, int n_in,
                              void* d_out, int out_size, void* d_ws, size_t ws_size,
                              hipStream_t stream) {
  const float* x    = (const float*)d_in[0];
  const float* W_ih = (const float*)d_in[1];
  const float* W_hh = (const float*)d_in[2];
  const float* b_ih = (const float*)d_in[3];
  const float* b_hh = (const float*)d_in[4];
  const float* W0   = (const float*)d_in[5];
  const float* b0   = (const float*)d_in[6];
  const float* W1   = (const float*)d_in[7];
  const float* b1   = (const float*)d_in[8];
  float* out = (float*)d_out;
  lstm_mfma<<<512, 256, 0, stream>>>(x, W_ih, W_hh, b_ih, b_hh, W0, b0, W1, b1, out);
}